// Round 1
// baseline (329.668 us; speedup 1.0000x reference)
//
#include <hip/hip_runtime.h>
#include <stdint.h>

#define BB 2
#define DD 64
#define HH 128
#define WW 128
#define NVOX (DD*HH*WW)        // 1048576 per batch (2^20)
#define TOTAL (BB*NVOX)        // 2097152
#define INF_I (1<<29)
#define HBINS 36868            // > max finite dsq (36227), padded
#define TX 16
#define LBINS 4096

// ---------------- edges: m & ~erosion(m), 6-neighborhood, border=False ----
__global__ void edges_kernel(const float* __restrict__ pred,
                             const float* __restrict__ targ,
                             uint8_t* __restrict__ ep,
                             uint8_t* __restrict__ eg)
{
    int idx = blockIdx.x * blockDim.x + threadIdx.x;
    if (idx >= TOTAL) return;
    int x = idx & (WW-1);
    int y = (idx >> 7) & (HH-1);
    int z = (idx >> 14) & (DD-1);

    const float* srcs[2] = {pred, targ};
    uint8_t* dsts[2] = {ep, eg};
    #pragma unroll
    for (int s = 0; s < 2; ++s) {
        const float* src = srcs[s];
        bool m = src[idx] > 0.5f;
        bool edge = false;
        if (m) {
            bool er = true;
            er = er && (x > 0)     && (src[idx - 1]     > 0.5f);
            er = er && (x < WW-1)  && (src[idx + 1]     > 0.5f);
            er = er && (y > 0)     && (src[idx - WW]    > 0.5f);
            er = er && (y < HH-1)  && (src[idx + WW]    > 0.5f);
            er = er && (z > 0)     && (src[idx - HH*WW] > 0.5f);
            er = er && (z < DD-1)  && (src[idx + HH*WW] > 0.5f);
            edge = !er;
        }
        dsts[s][idx] = (uint8_t)edge;
    }
}

// ---------------- EDT pass along x (from binary mask) ---------------------
__global__ void edt_pass_x(const uint8_t* __restrict__ mask, int* __restrict__ d)
{
    __shared__ int f[WW];
    int line = blockIdx.x;              // (b,z,y) flattened: 0..BB*DD*HH-1
    size_t base = (size_t)line * WW;
    int i = threadIdx.x;                // 0..127
    f[i] = mask[base + i] ? 0 : INF_I;
    __syncthreads();
    int best = INF_I;
    #pragma unroll 8
    for (int j = 0; j < WW; ++j) {
        int diff = i - j;
        best = min(best, f[j] + diff*diff);
    }
    d[base + i] = best;
}

// ---------------- EDT pass along y (in-place, LDS tile) --------------------
__global__ void edt_pass_y(int* __restrict__ d)
{
    __shared__ int tile[HH][TX];
    int blk = blockIdx.x;               // (b*DD + z)*(WW/TX) + xt
    int xt = blk % (WW/TX);
    int bz = blk / (WW/TX);
    size_t base = (size_t)bz * (HH*WW) + (size_t)xt*TX;
    int tid = threadIdx.x;              // 256
    for (int t = tid; t < HH*TX; t += 256) {
        int yy = t / TX, xx = t % TX;
        tile[yy][xx] = d[base + (size_t)yy*WW + xx];
    }
    __syncthreads();
    int g  = tid / TX;                  // 0..15 y-group
    int xx = tid % TX;
    int best[8];
    #pragma unroll
    for (int k = 0; k < 8; ++k) best[k] = INF_I;
    for (int j = 0; j < HH; ++j) {
        int v = tile[j][xx];
        int dj = g - j;
        #pragma unroll
        for (int k = 0; k < 8; ++k) {
            int diff = dj + k*16;
            best[k] = min(best[k], v + diff*diff);
        }
    }
    #pragma unroll
    for (int k = 0; k < 8; ++k)
        d[base + (size_t)(g + k*16)*WW + xx] = best[k];
}

// ---------------- EDT pass along z (in-place, LDS tile) --------------------
__global__ void edt_pass_z(int* __restrict__ d)
{
    __shared__ int tile[DD][TX];
    int blk = blockIdx.x;               // (b*HH + y)*(WW/TX) + xt
    int xt = blk % (WW/TX);
    int rest = blk / (WW/TX);           // b*HH + y
    int y = rest % HH;
    int b = rest / HH;
    size_t base = (size_t)b * NVOX + (size_t)y*WW + (size_t)xt*TX;
    int tid = threadIdx.x;              // 256
    for (int t = tid; t < DD*TX; t += 256) {
        int zz = t / TX, xx = t % TX;
        tile[zz][xx] = d[base + (size_t)zz*(HH*WW) + xx];
    }
    __syncthreads();
    int g  = tid / TX;                  // 0..15 z-group
    int xx = tid % TX;
    int best[4];
    #pragma unroll
    for (int k = 0; k < 4; ++k) best[k] = INF_I;
    for (int j = 0; j < DD; ++j) {
        int v = tile[j][xx];
        int dj = g - j;
        #pragma unroll
        for (int k = 0; k < 4; ++k) {
            int diff = dj + k*16;
            best[k] = min(best[k], v + diff*diff);
        }
    }
    #pragma unroll
    for (int k = 0; k < 4; ++k)
        d[base + (size_t)(g + k*16)*(HH*WW) + xx] = best[k];
}

// ---------------- histogram of dsq over masked voxels ----------------------
__global__ void hist_kernel(const uint8_t* __restrict__ mask,
                            const int* __restrict__ d,
                            int* __restrict__ hist, int dir)
{
    __shared__ int lh[LBINS];
    int tid = threadIdx.x;
    for (int t = tid; t < LBINS; t += 256) lh[t] = 0;
    __syncthreads();
    int idx = blockIdx.x * 256 + tid;
    int b = idx >> 20;                  // NVOX = 2^20
    if (idx < TOTAL && mask[idx]) {
        int v = d[idx];
        if (v >= HBINS) v = HBINS - 1;
        if (v < LBINS) atomicAdd(&lh[v], 1);
        else atomicAdd(&hist[(size_t)(b*2 + dir)*HBINS + v], 1);
    }
    __syncthreads();
    int bb = (blockIdx.x * 256) >> 20;  // whole block in same batch
    int* gh = &hist[(size_t)(bb*2 + dir)*HBINS];
    for (int t = tid; t < LBINS; t += 256) {
        int c = lh[t];
        if (c) atomicAdd(&gh[t], c);
    }
}

// ---------------- percentile (torch.quantile-style linear interp) ----------
__global__ void percentile_kernel(const int* __restrict__ hist, float* __restrict__ h)
{
    __shared__ int ps[256];
    __shared__ int abin, bbin;
    int g = blockIdx.x;                 // b*2 + dir
    const int* gh = &hist[(size_t)g * HBINS];
    int tid = threadIdx.x;              // 256
    const int CH = (HBINS + 255) / 256; // 145
    int start = tid * CH;
    int end = start + CH; if (end > HBINS) end = HBINS;
    int part = 0;
    for (int t = start; t < end; ++t) part += gh[t];
    ps[tid] = part;
    __syncthreads();
    // Hillis-Steele inclusive scan over 256 partials
    for (int off = 1; off < 256; off <<= 1) {
        int v = (tid >= off) ? ps[tid - off] : 0;
        __syncthreads();
        ps[tid] += v;
        __syncthreads();
    }
    int n = ps[255];
    float pos = 0.95f * (float)(n - 1);
    float fpos = floorf(pos);
    int lo = (int)fpos;
    int nm1 = n - 1; if (nm1 < 0) nm1 = 0;
    if (lo < 0) lo = 0;
    if (lo > nm1) lo = nm1;
    int hi = lo + 1; if (hi > nm1) hi = nm1;
    float frac = pos - fpos;

    int incl = ps[tid];
    int excl = incl - part;
    if (lo >= excl && lo < incl) {
        int cum = excl;
        for (int t = start; t < end; ++t) { cum += gh[t]; if (cum > lo) { abin = t; break; } }
    }
    if (hi >= excl && hi < incl) {
        int cum = excl;
        for (int t = start; t < end; ++t) { cum += gh[t]; if (cum > hi) { bbin = t; break; } }
    }
    __syncthreads();
    if (tid == 0) {
        float a = sqrtf((float)abin);
        float bv = sqrtf((float)bbin);
        h[g] = a + frac * (bv - a);
    }
}

// ---------------- final: non-directed HD95 = max of the two directions -----
__global__ void final_kernel(const float* __restrict__ h, float* __restrict__ out)
{
    int b = threadIdx.x;
    if (b < BB) out[b] = fmaxf(h[b*2 + 0], h[b*2 + 1]);
}

extern "C" void kernel_launch(void* const* d_in, const int* in_sizes, int n_in,
                              void* d_out, int out_size, void* d_ws, size_t ws_size,
                              hipStream_t stream)
{
    const float* pred = (const float*)d_in[0];
    const float* targ = (const float*)d_in[1];
    float* out = (float*)d_out;

    uint8_t* ws = (uint8_t*)d_ws;
    uint8_t* ep = ws;                       // TOTAL bytes
    uint8_t* eg = ep + TOTAL;               // TOTAL bytes
    int* dbuf   = (int*)(eg + TOTAL);       // TOTAL * 4 bytes
    int* hist   = dbuf + TOTAL;             // 4 * HBINS * 4 bytes
    float* h    = (float*)(hist + 4*HBINS); // 4 floats

    hipMemsetAsync(hist, 0, (size_t)4 * HBINS * sizeof(int), stream);

    edges_kernel<<<TOTAL/256, 256, 0, stream>>>(pred, targ, ep, eg);

    // EDT of gt edges -> distances evaluated at pred edges (dir 0)
    edt_pass_x<<<BB*DD*HH, WW, 0, stream>>>(eg, dbuf);
    edt_pass_y<<<BB*DD*(WW/TX), 256, 0, stream>>>(dbuf);
    edt_pass_z<<<BB*HH*(WW/TX), 256, 0, stream>>>(dbuf);
    hist_kernel<<<TOTAL/256, 256, 0, stream>>>(ep, dbuf, hist, 0);

    // EDT of pred edges -> distances evaluated at gt edges (dir 1)
    edt_pass_x<<<BB*DD*HH, WW, 0, stream>>>(ep, dbuf);
    edt_pass_y<<<BB*DD*(WW/TX), 256, 0, stream>>>(dbuf);
    edt_pass_z<<<BB*HH*(WW/TX), 256, 0, stream>>>(dbuf);
    hist_kernel<<<TOTAL/256, 256, 0, stream>>>(eg, dbuf, hist, 1);

    percentile_kernel<<<4, 256, 0, stream>>>(hist, h);
    final_kernel<<<1, 64, 0, stream>>>(h, out);
}

// Round 2
// 271.313 us; speedup vs baseline: 1.2151x; 1.2151x over previous
//
#include <hip/hip_runtime.h>
#include <stdint.h>

#define BB 2
#define DD 64
#define HH 128
#define WW 128
#define NVOX (DD*HH*WW)        // 1048576 per batch (2^20)
#define TOTAL (BB*NVOX)        // 2097152
#define INF_I (1<<29)
#define HBINS 36868            // > max finite dsq (36227), padded
#define LBINS 4096

// ---------------- edges: m & ~erosion(m), 6-neighborhood, border=False ----
__global__ void edges_kernel(const float* __restrict__ pred,
                             const float* __restrict__ targ,
                             uint8_t* __restrict__ ep,
                             uint8_t* __restrict__ eg)
{
    int idx = blockIdx.x * blockDim.x + threadIdx.x;
    if (idx >= TOTAL) return;
    int x = idx & (WW-1);
    int y = (idx >> 7) & (HH-1);
    int z = (idx >> 14) & (DD-1);

    const float* srcs[2] = {pred, targ};
    uint8_t* dsts[2] = {ep, eg};
    #pragma unroll
    for (int s = 0; s < 2; ++s) {
        const float* src = srcs[s];
        bool m = src[idx] > 0.5f;
        bool edge = false;
        if (m) {
            bool er = true;
            er = er && (x > 0)     && (src[idx - 1]     > 0.5f);
            er = er && (x < WW-1)  && (src[idx + 1]     > 0.5f);
            er = er && (y > 0)     && (src[idx - WW]    > 0.5f);
            er = er && (y < HH-1)  && (src[idx + WW]    > 0.5f);
            er = er && (z > 0)     && (src[idx - HH*WW] > 0.5f);
            er = er && (z < DD-1)  && (src[idx + HH*WW] > 0.5f);
            edge = !er;
        }
        dsts[s][idx] = (uint8_t)edge;
    }
}

// ---------------- EDT pass along x (binary mask -> dsq), early-exit -------
__global__ void edt_pass_x(const uint8_t* __restrict__ mask, int* __restrict__ d)
{
    __shared__ uint8_t f[WW];
    int line = blockIdx.x;              // (b,z,y) flattened
    size_t base = (size_t)line * WW;
    int i = threadIdx.x;                // 0..127
    uint8_t me = mask[base + i];
    f[i] = me;
    __syncthreads();
    int best = INF_I;
    if (me) {
        best = 0;
    } else {
        for (int o = 1; o < WW; ++o) {
            bool L = (i - o >= 0) && f[i - o];
            bool R = (i + o < WW) && f[i + o];
            if (L || R) { best = o * o; break; }
        }
    }
    d[base + i] = best;
}

// ---------------- EDT pass along y (in-place, LDS tile, early-exit) -------
// tile: full y-extent (128) x 8 consecutive x. 1024 threads, 1 out/thread.
#define TXY 8
__global__ void edt_pass_y(int* __restrict__ d)
{
    __shared__ int tile[HH * TXY];
    int blk = blockIdx.x;               // (b*DD + z)*(WW/TXY) + xt
    int xt = blk % (WW / TXY);
    int bz = blk / (WW / TXY);
    size_t base = (size_t)bz * (HH * WW) + (size_t)xt * TXY;
    int tid = threadIdx.x;              // 1024
    int yy = tid >> 3, xx = tid & (TXY - 1);
    int v0 = d[base + (size_t)yy * WW + xx];
    tile[tid] = v0;
    __syncthreads();
    int best = v0;
    for (int o = 1; o < HH && o * o < best; ++o) {
        int osq = o * o;
        int lo = yy - o, hi = yy + o;
        if (lo >= 0) best = min(best, tile[lo * TXY + xx] + osq);
        if (hi < HH) best = min(best, tile[hi * TXY + xx] + osq);
    }
    d[base + (size_t)yy * WW + xx] = best;
}

// ---------------- EDT pass along z (in-place, LDS tile, early-exit) -------
// tile: full z-extent (64) x 16 consecutive x. 1024 threads, 1 out/thread.
#define TXZ 16
__global__ void edt_pass_z(int* __restrict__ d)
{
    __shared__ int tile[DD * TXZ];
    int blk = blockIdx.x;               // (b*HH + y)*(WW/TXZ) + xt
    int xt = blk % (WW / TXZ);
    int rest = blk / (WW / TXZ);        // b*HH + y
    int y = rest % HH;
    int b = rest / HH;
    size_t base = (size_t)b * NVOX + (size_t)y * WW + (size_t)xt * TXZ;
    int tid = threadIdx.x;              // 1024
    int zz = tid >> 4, xx = tid & (TXZ - 1);
    int v0 = d[base + (size_t)zz * (HH * WW) + xx];
    tile[tid] = v0;
    __syncthreads();
    int best = v0;
    for (int o = 1; o < DD && o * o < best; ++o) {
        int osq = o * o;
        int lo = zz - o, hi = zz + o;
        if (lo >= 0) best = min(best, tile[lo * TXZ + xx] + osq);
        if (hi < DD) best = min(best, tile[hi * TXZ + xx] + osq);
    }
    d[base + (size_t)zz * (HH * WW) + xx] = best;
}

// ---------------- histogram of dsq over masked voxels ----------------------
// Wave-aggregated: one LDS atomic per (wave x distinct value).
__global__ void hist_kernel(const uint8_t* __restrict__ mask,
                            const int* __restrict__ d,
                            int* __restrict__ hist, int dir)
{
    __shared__ int lh[LBINS];
    int tid = threadIdx.x;
    for (int t = tid; t < LBINS; t += 256) lh[t] = 0;
    __syncthreads();

    int idx = blockIdx.x * 256 + tid;
    int bb = (blockIdx.x * 256) >> 20;  // whole block in same batch (NVOX=2^20)
    int* gh = &hist[(size_t)(bb * 2 + dir) * HBINS];

    int lane = tid & 63;
    bool valid = (idx < TOTAL) && mask[idx];
    int v = -1;
    if (valid) {
        v = d[idx];
        if (v >= HBINS) v = HBINS - 1;
    }
    unsigned long long active = __ballot(valid);
    while (active) {
        int leader = __ffsll((unsigned long long)active) - 1;
        int lv = __shfl(v, leader);
        unsigned long long same = __ballot(valid && (v == lv));
        if (lane == leader) {
            int cnt = __popcll(same);
            if (lv < LBINS) atomicAdd(&lh[lv], cnt);
            else            atomicAdd(&gh[lv], cnt);
        }
        active &= ~same;
    }
    __syncthreads();
    for (int t = tid; t < LBINS; t += 256) {
        int c = lh[t];
        if (c) atomicAdd(&gh[t], c);
    }
}

// ---------------- percentile (torch.quantile-style linear interp) ----------
__global__ void percentile_kernel(const int* __restrict__ hist, float* __restrict__ h)
{
    __shared__ int ps[256];
    __shared__ int abin, bbin;
    int g = blockIdx.x;                 // b*2 + dir
    const int* gh = &hist[(size_t)g * HBINS];
    int tid = threadIdx.x;              // 256
    const int CH = (HBINS + 255) / 256; // 145
    int start = tid * CH;
    int end = start + CH; if (end > HBINS) end = HBINS;
    int part = 0;
    for (int t = start; t < end; ++t) part += gh[t];
    ps[tid] = part;
    __syncthreads();
    for (int off = 1; off < 256; off <<= 1) {
        int v = (tid >= off) ? ps[tid - off] : 0;
        __syncthreads();
        ps[tid] += v;
        __syncthreads();
    }
    int n = ps[255];
    float pos = 0.95f * (float)(n - 1);
    float fpos = floorf(pos);
    int lo = (int)fpos;
    int nm1 = n - 1; if (nm1 < 0) nm1 = 0;
    if (lo < 0) lo = 0;
    if (lo > nm1) lo = nm1;
    int hi = lo + 1; if (hi > nm1) hi = nm1;
    float frac = pos - fpos;

    int incl = ps[tid];
    int excl = incl - part;
    if (lo >= excl && lo < incl) {
        int cum = excl;
        for (int t = start; t < end; ++t) { cum += gh[t]; if (cum > lo) { abin = t; break; } }
    }
    if (hi >= excl && hi < incl) {
        int cum = excl;
        for (int t = start; t < end; ++t) { cum += gh[t]; if (cum > hi) { bbin = t; break; } }
    }
    __syncthreads();
    if (tid == 0) {
        float a = sqrtf((float)abin);
        float bv = sqrtf((float)bbin);
        h[g] = a + frac * (bv - a);
    }
}

// ---------------- final: non-directed HD95 = max of the two directions -----
__global__ void final_kernel(const float* __restrict__ h, float* __restrict__ out)
{
    int b = threadIdx.x;
    if (b < BB) out[b] = fmaxf(h[b*2 + 0], h[b*2 + 1]);
}

extern "C" void kernel_launch(void* const* d_in, const int* in_sizes, int n_in,
                              void* d_out, int out_size, void* d_ws, size_t ws_size,
                              hipStream_t stream)
{
    const float* pred = (const float*)d_in[0];
    const float* targ = (const float*)d_in[1];
    float* out = (float*)d_out;

    uint8_t* ws = (uint8_t*)d_ws;
    uint8_t* ep = ws;                       // TOTAL bytes
    uint8_t* eg = ep + TOTAL;               // TOTAL bytes
    int* dbuf   = (int*)(eg + TOTAL);       // TOTAL * 4 bytes
    int* hist   = dbuf + TOTAL;             // 4 * HBINS * 4 bytes
    float* h    = (float*)(hist + 4*HBINS); // 4 floats

    hipMemsetAsync(hist, 0, (size_t)4 * HBINS * sizeof(int), stream);

    edges_kernel<<<TOTAL/256, 256, 0, stream>>>(pred, targ, ep, eg);

    // EDT of gt edges -> distances evaluated at pred edges (dir 0)
    edt_pass_x<<<BB*DD*HH, WW, 0, stream>>>(eg, dbuf);
    edt_pass_y<<<BB*DD*(WW/TXY), 1024, 0, stream>>>(dbuf);
    edt_pass_z<<<BB*HH*(WW/TXZ), 1024, 0, stream>>>(dbuf);
    hist_kernel<<<TOTAL/256, 256, 0, stream>>>(ep, dbuf, hist, 0);

    // EDT of pred edges -> distances evaluated at gt edges (dir 1)
    edt_pass_x<<<BB*DD*HH, WW, 0, stream>>>(ep, dbuf);
    edt_pass_y<<<BB*DD*(WW/TXY), 1024, 0, stream>>>(dbuf);
    edt_pass_z<<<BB*HH*(WW/TXZ), 1024, 0, stream>>>(dbuf);
    hist_kernel<<<TOTAL/256, 256, 0, stream>>>(eg, dbuf, hist, 1);

    percentile_kernel<<<4, 256, 0, stream>>>(hist, h);
    final_kernel<<<1, 64, 0, stream>>>(h, out);
}

// Round 3
// 172.868 us; speedup vs baseline: 1.9070x; 1.5695x over previous
//
#include <hip/hip_runtime.h>
#include <stdint.h>

#define BB 2
#define DD 64
#define HH 128
#define WW 128
#define NVOX (DD*HH*WW)        // 1048576 per batch (2^20)
#define TOTAL (BB*NVOX)        // 2097152
#define INF_I (1<<29)
#define HBINS 36868            // > max finite dsq (36227), padded
#define LBINS 4096
#define NSMALL 7               // shadow slots (LBINS bins each); slot0 = full

// ---------------- edges: m & ~erosion(m), 6-neighborhood, border=False ----
// float4-vectorized: each thread does 4 x-consecutive voxels, packs 4 bytes.
__global__ void edges_kernel(const float* __restrict__ pred,
                             const float* __restrict__ targ,
                             uint32_t* __restrict__ ep,
                             uint32_t* __restrict__ eg)
{
    int i = blockIdx.x * blockDim.x + threadIdx.x;   // quad index
    if (i >= TOTAL/4) return;
    int idx = i * 4;
    int x0 = idx & (WW-1);
    int y  = (idx >> 7) & (HH-1);
    int z  = (idx >> 14) & (DD-1);

    const float* srcs[2] = {pred, targ};
    uint32_t* dsts[2] = {ep, eg};
    const float4 zero4 = make_float4(0.f, 0.f, 0.f, 0.f);
    #pragma unroll
    for (int s = 0; s < 2; ++s) {
        const float* src = srcs[s];
        const float4* src4 = (const float4*)src;
        float4 c = src4[i];
        float lft = (x0 > 0)      ? src[idx - 1] : 0.f;
        float rgt = (x0 + 4 < WW) ? src[idx + 4] : 0.f;
        float4 ym = (y > 0)    ? src4[i - WW/4]      : zero4;
        float4 yp = (y < HH-1) ? src4[i + WW/4]      : zero4;
        float4 zm = (z > 0)    ? src4[i - (HH*WW)/4] : zero4;
        float4 zp = (z < DD-1) ? src4[i + (HH*WW)/4] : zero4;
        bool m0 = c.x > 0.5f, m1 = c.y > 0.5f, m2 = c.z > 0.5f, m3 = c.w > 0.5f;
        bool e0 = m0 && !((lft>0.5f) && m1 && (ym.x>0.5f) && (yp.x>0.5f) && (zm.x>0.5f) && (zp.x>0.5f));
        bool e1 = m1 && !(m0 && m2 && (ym.y>0.5f) && (yp.y>0.5f) && (zm.y>0.5f) && (zp.y>0.5f));
        bool e2 = m2 && !(m1 && m3 && (ym.z>0.5f) && (yp.z>0.5f) && (zm.z>0.5f) && (zp.z>0.5f));
        bool e3 = m3 && !(m2 && (rgt>0.5f) && (ym.w>0.5f) && (yp.w>0.5f) && (zm.w>0.5f) && (zp.w>0.5f));
        dsts[s][i] = (uint32_t)e0 | ((uint32_t)e1 << 8) | ((uint32_t)e2 << 16) | ((uint32_t)e3 << 24);
    }
}

// ---------------- EDT pass along x (binary mask -> dsq), early-exit -------
__global__ void edt_pass_x(const uint8_t* __restrict__ mask, int* __restrict__ d)
{
    __shared__ int f[WW];
    int line = blockIdx.x;              // (b,z,y) flattened
    size_t base = (size_t)line * WW;
    int i = threadIdx.x;                // 0..127
    int me = mask[base + i];
    f[i] = me;
    __syncthreads();
    int best = INF_I;
    if (me) {
        best = 0;
    } else {
        for (int o = 1; o < WW; ++o) {
            bool L = (i - o >= 0) && f[i - o];
            bool R = (i + o < WW) && f[i + o];
            if (L || R) { best = o * o; break; }
        }
    }
    d[base + i] = best;
}

// ---------------- EDT pass along y (in-place, LDS tile, early-exit) -------
#define TXY 8
__global__ void edt_pass_y(int* __restrict__ d)
{
    __shared__ int tile[HH * TXY];
    int blk = blockIdx.x;               // (b*DD + z)*(WW/TXY) + xt
    int xt = blk % (WW / TXY);
    int bz = blk / (WW / TXY);
    size_t base = (size_t)bz * (HH * WW) + (size_t)xt * TXY;
    int tid = threadIdx.x;              // 1024
    int yy = tid >> 3, xx = tid & (TXY - 1);
    int v0 = d[base + (size_t)yy * WW + xx];
    tile[tid] = v0;
    __syncthreads();
    int best = v0;
    for (int o = 1; o < HH && o * o < best; ++o) {
        int osq = o * o;
        int lo = yy - o, hi = yy + o;
        if (lo >= 0) best = min(best, tile[lo * TXY + xx] + osq);
        if (hi < HH) best = min(best, tile[hi * TXY + xx] + osq);
    }
    d[base + (size_t)yy * WW + xx] = best;
}

// -------- EDT pass along z fused with histogram of dsq at mask voxels ------
#define TXZ 16
__global__ void edt_pass_z_hist(const int* __restrict__ d,
                                const uint8_t* __restrict__ mask,
                                int* __restrict__ bigh,
                                int* __restrict__ smallh,
                                int dir)
{
    __shared__ int tile[DD * TXZ];
    __shared__ int lh[LBINS];
    int tid = threadIdx.x;              // 1024
    for (int t = tid; t < LBINS; t += 1024) lh[t] = 0;

    int blk = blockIdx.x;               // (b*HH + y)*(WW/TXZ) + xt
    int xt = blk % (WW / TXZ);
    int rest = blk / (WW / TXZ);        // b*HH + y
    int y = rest % HH;
    int b = rest / HH;
    size_t base = (size_t)b * NVOX + (size_t)y * WW + (size_t)xt * TXZ;
    int zz = tid >> 4, xx = tid & (TXZ - 1);
    size_t off = base + (size_t)zz * (HH * WW) + xx;
    int v0 = d[off];
    tile[tid] = v0;
    bool valid = mask[off] != 0;
    __syncthreads();

    int best = v0;
    for (int o = 1; o < DD && o * o < best; ++o) {
        int osq = o * o;
        int lo = zz - o, hi = zz + o;
        if (lo >= 0) best = min(best, tile[lo * TXZ + xx] + osq);
        if (hi < DD) best = min(best, tile[hi * TXZ + xx] + osq);
    }
    // final squared distance for this voxel is `best`; histogram it directly
    int g = b * 2 + dir;
    int* gbig = bigh + (size_t)g * HBINS;
    int v = best; if (v >= HBINS) v = HBINS - 1;
    int lane = tid & 63;
    unsigned long long active = __ballot(valid);
    while (active) {
        int leader = __ffsll(active) - 1;
        int lv = __shfl(v, leader);
        unsigned long long same = __ballot(valid && (v == lv));
        if (lane == leader) {
            int cnt = __popcll(same);
            if (lv < LBINS) atomicAdd(&lh[lv], cnt);
            else            atomicAdd(&gbig[lv], cnt);
        }
        active &= ~same;
    }
    __syncthreads();
    int slot = blockIdx.x & 7;
    int* dst = (slot == 0) ? gbig : (smallh + ((size_t)g * NSMALL + (slot - 1)) * LBINS);
    for (int t = tid; t < LBINS; t += 1024) {
        int c = lh[t];
        if (c) atomicAdd(&dst[t], c);
    }
}

// ---------------- percentile (torch.quantile-style linear interp) ----------
__device__ __forceinline__ int bincnt(const int* __restrict__ gbig,
                                      const int* __restrict__ gsmall, int t)
{
    int c = gbig[t];
    if (t < LBINS) {
        #pragma unroll
        for (int s = 0; s < NSMALL; ++s) c += gsmall[s * LBINS + t];
    }
    return c;
}

__global__ void percentile_kernel(const int* __restrict__ bigh,
                                  const int* __restrict__ smallh,
                                  float* __restrict__ h)
{
    __shared__ int ps[256];
    __shared__ int abin, bbin;
    int g = blockIdx.x;                 // b*2 + dir
    const int* gbig = bigh + (size_t)g * HBINS;
    const int* gsmall = smallh + (size_t)g * NSMALL * LBINS;
    int tid = threadIdx.x;              // 256
    const int CH = (HBINS + 255) / 256; // 145
    int start = tid * CH;
    int end = start + CH; if (end > HBINS) end = HBINS;
    int part = 0;
    for (int t = start; t < end; ++t) part += bincnt(gbig, gsmall, t);
    ps[tid] = part;
    __syncthreads();
    for (int off = 1; off < 256; off <<= 1) {
        int v = (tid >= off) ? ps[tid - off] : 0;
        __syncthreads();
        ps[tid] += v;
        __syncthreads();
    }
    int n = ps[255];
    float pos = 0.95f * (float)(n - 1);
    float fpos = floorf(pos);
    int lo = (int)fpos;
    int nm1 = n - 1; if (nm1 < 0) nm1 = 0;
    if (lo < 0) lo = 0;
    if (lo > nm1) lo = nm1;
    int hi = lo + 1; if (hi > nm1) hi = nm1;
    float frac = pos - fpos;

    int incl = ps[tid];
    int excl = incl - part;
    if (lo >= excl && lo < incl) {
        int cum = excl;
        for (int t = start; t < end; ++t) { cum += bincnt(gbig, gsmall, t); if (cum > lo) { abin = t; break; } }
    }
    if (hi >= excl && hi < incl) {
        int cum = excl;
        for (int t = start; t < end; ++t) { cum += bincnt(gbig, gsmall, t); if (cum > hi) { bbin = t; break; } }
    }
    __syncthreads();
    if (tid == 0) {
        float a = sqrtf((float)abin);
        float bv = sqrtf((float)bbin);
        h[g] = a + frac * (bv - a);
    }
}

// ---------------- final: non-directed HD95 = max of the two directions -----
__global__ void final_kernel(const float* __restrict__ h, float* __restrict__ out)
{
    int b = threadIdx.x;
    if (b < BB) out[b] = fmaxf(h[b*2 + 0], h[b*2 + 1]);
}

extern "C" void kernel_launch(void* const* d_in, const int* in_sizes, int n_in,
                              void* d_out, int out_size, void* d_ws, size_t ws_size,
                              hipStream_t stream)
{
    const float* pred = (const float*)d_in[0];
    const float* targ = (const float*)d_in[1];
    float* out = (float*)d_out;

    uint8_t* ws = (uint8_t*)d_ws;
    uint8_t* ep = ws;                          // TOTAL bytes
    uint8_t* eg = ep + TOTAL;                  // TOTAL bytes
    int* dbuf   = (int*)(eg + TOTAL);          // TOTAL ints
    int* bigh   = dbuf + TOTAL;                // 4 * HBINS ints
    int* smallh = bigh + 4 * HBINS;            // 4 * NSMALL * LBINS ints
    float* h    = (float*)(smallh + 4 * NSMALL * LBINS); // 4 floats

    hipMemsetAsync(bigh, 0, ((size_t)4 * HBINS + (size_t)4 * NSMALL * LBINS) * sizeof(int), stream);

    edges_kernel<<<(TOTAL/4)/256, 256, 0, stream>>>(pred, targ, (uint32_t*)ep, (uint32_t*)eg);

    // dir 0: EDT of gt edges, histogrammed at pred-edge voxels
    edt_pass_x<<<BB*DD*HH, WW, 0, stream>>>(eg, dbuf);
    edt_pass_y<<<BB*DD*(WW/TXY), 1024, 0, stream>>>(dbuf);
    edt_pass_z_hist<<<BB*HH*(WW/TXZ), 1024, 0, stream>>>(dbuf, ep, bigh, smallh, 0);

    // dir 1: EDT of pred edges, histogrammed at gt-edge voxels
    edt_pass_x<<<BB*DD*HH, WW, 0, stream>>>(ep, dbuf);
    edt_pass_y<<<BB*DD*(WW/TXY), 1024, 0, stream>>>(dbuf);
    edt_pass_z_hist<<<BB*HH*(WW/TXZ), 1024, 0, stream>>>(dbuf, eg, bigh, smallh, 1);

    percentile_kernel<<<4, 256, 0, stream>>>(bigh, smallh, h);
    final_kernel<<<1, 64, 0, stream>>>(h, out);
}

// Round 4
// 112.986 us; speedup vs baseline: 2.9178x; 1.5300x over previous
//
#include <hip/hip_runtime.h>
#include <stdint.h>

#define BB 2
#define DD 64
#define HH 128
#define WW 128
#define NVOX (DD*HH*WW)        // 1048576 per batch (2^20)
#define TOTAL (BB*NVOX)        // 2097152
#define INF_I (1<<29)
#define HBINS 36868            // > max finite dsq (36227), padded
#define LBINS 4096
#define NSMALL 7               // shadow slots (LBINS bins each); slot0 = full
#define CHUNK 256
#define NCH ((HBINS + CHUNK - 1) / CHUNK)   // 145

// ---------------- edges: m & ~erosion(m), 6-neighborhood, border=False ----
__global__ void edges_kernel(const float* __restrict__ pred,
                             const float* __restrict__ targ,
                             uint32_t* __restrict__ ep,
                             uint32_t* __restrict__ eg)
{
    int i = blockIdx.x * blockDim.x + threadIdx.x;   // quad index
    if (i >= TOTAL/4) return;
    int idx = i * 4;
    int x0 = idx & (WW-1);
    int y  = (idx >> 7) & (HH-1);
    int z  = (idx >> 14) & (DD-1);

    const float* srcs[2] = {pred, targ};
    uint32_t* dsts[2] = {ep, eg};
    const float4 zero4 = make_float4(0.f, 0.f, 0.f, 0.f);
    #pragma unroll
    for (int s = 0; s < 2; ++s) {
        const float* src = srcs[s];
        const float4* src4 = (const float4*)src;
        float4 c = src4[i];
        float lft = (x0 > 0)      ? src[idx - 1] : 0.f;
        float rgt = (x0 + 4 < WW) ? src[idx + 4] : 0.f;
        float4 ym = (y > 0)    ? src4[i - WW/4]      : zero4;
        float4 yp = (y < HH-1) ? src4[i + WW/4]      : zero4;
        float4 zm = (z > 0)    ? src4[i - (HH*WW)/4] : zero4;
        float4 zp = (z < DD-1) ? src4[i + (HH*WW)/4] : zero4;
        bool m0 = c.x > 0.5f, m1 = c.y > 0.5f, m2 = c.z > 0.5f, m3 = c.w > 0.5f;
        bool e0 = m0 && !((lft>0.5f) && m1 && (ym.x>0.5f) && (yp.x>0.5f) && (zm.x>0.5f) && (zp.x>0.5f));
        bool e1 = m1 && !(m0 && m2 && (ym.y>0.5f) && (yp.y>0.5f) && (zm.y>0.5f) && (zp.y>0.5f));
        bool e2 = m2 && !(m1 && m3 && (ym.z>0.5f) && (yp.z>0.5f) && (zm.z>0.5f) && (zp.z>0.5f));
        bool e3 = m3 && !(m2 && (rgt>0.5f) && (ym.w>0.5f) && (yp.w>0.5f) && (zm.w>0.5f) && (zp.w>0.5f));
        dsts[s][i] = (uint32_t)e0 | ((uint32_t)e1 << 8) | ((uint32_t)e2 << 16) | ((uint32_t)e3 << 24);
    }
}

// ---------------- EDT pass along x (binary mask -> dsq), early-exit -------
__global__ void edt_pass_x(const uint8_t* __restrict__ mask, int* __restrict__ d)
{
    __shared__ int f[WW];
    int line = blockIdx.x;              // (b,z,y) flattened
    size_t base = (size_t)line * WW;
    int i = threadIdx.x;                // 0..127
    int me = mask[base + i];
    f[i] = me;
    __syncthreads();
    int best = INF_I;
    if (me) {
        best = 0;
    } else {
        for (int o = 1; o < WW; ++o) {
            bool L = (i - o >= 0) && f[i - o];
            bool R = (i + o < WW) && f[i + o];
            if (L || R) { best = o * o; break; }
        }
    }
    d[base + i] = best;
}

// ---------------- EDT pass along y (in-place, LDS tile, early-exit) -------
#define TXY 8
__global__ void edt_pass_y(int* __restrict__ d)
{
    __shared__ int tile[HH * TXY];
    int blk = blockIdx.x;               // (b*DD + z)*(WW/TXY) + xt
    int xt = blk % (WW / TXY);
    int bz = blk / (WW / TXY);
    size_t base = (size_t)bz * (HH * WW) + (size_t)xt * TXY;
    int tid = threadIdx.x;              // 1024
    int yy = tid >> 3, xx = tid & (TXY - 1);
    int v0 = d[base + (size_t)yy * WW + xx];
    tile[tid] = v0;
    __syncthreads();
    int best = v0;
    for (int o = 1; o < HH && o * o < best; ++o) {
        int osq = o * o;
        int lo = yy - o, hi = yy + o;
        if (lo >= 0) best = min(best, tile[lo * TXY + xx] + osq);
        if (hi < HH) best = min(best, tile[hi * TXY + xx] + osq);
    }
    d[base + (size_t)yy * WW + xx] = best;
}

// -------- EDT pass along z fused with histogram of dsq at mask voxels ------
#define TXZ 16
__global__ void edt_pass_z_hist(const int* __restrict__ d,
                                const uint8_t* __restrict__ mask,
                                int* __restrict__ bigh,
                                int* __restrict__ smallh,
                                int dir)
{
    __shared__ int tile[DD * TXZ];
    __shared__ int lh[LBINS];
    int tid = threadIdx.x;              // 1024
    for (int t = tid; t < LBINS; t += 1024) lh[t] = 0;

    int blk = blockIdx.x;               // (b*HH + y)*(WW/TXZ) + xt
    int xt = blk % (WW / TXZ);
    int rest = blk / (WW / TXZ);        // b*HH + y
    int y = rest % HH;
    int b = rest / HH;
    size_t base = (size_t)b * NVOX + (size_t)y * WW + (size_t)xt * TXZ;
    int zz = tid >> 4, xx = tid & (TXZ - 1);
    size_t off = base + (size_t)zz * (HH * WW) + xx;
    int v0 = d[off];
    tile[tid] = v0;
    bool valid = mask[off] != 0;
    __syncthreads();

    int best = v0;
    for (int o = 1; o < DD && o * o < best; ++o) {
        int osq = o * o;
        int lo = zz - o, hi = zz + o;
        if (lo >= 0) best = min(best, tile[lo * TXZ + xx] + osq);
        if (hi < DD) best = min(best, tile[hi * TXZ + xx] + osq);
    }
    int g = b * 2 + dir;
    int* gbig = bigh + (size_t)g * HBINS;
    int v = best; if (v >= HBINS) v = HBINS - 1;
    int lane = tid & 63;
    unsigned long long active = __ballot(valid);
    while (active) {
        int leader = __ffsll(active) - 1;
        int lv = __shfl(v, leader);
        unsigned long long same = __ballot(valid && (v == lv));
        if (lane == leader) {
            int cnt = __popcll(same);
            if (lv < LBINS) atomicAdd(&lh[lv], cnt);
            else            atomicAdd(&gbig[lv], cnt);
        }
        active &= ~same;
    }
    __syncthreads();
    int slot = blockIdx.x & 7;
    int* dst = (slot == 0) ? gbig : (smallh + ((size_t)g * NSMALL + (slot - 1)) * LBINS);
    for (int t = tid; t < LBINS; t += 1024) {
        int c = lh[t];
        if (c) atomicAdd(&dst[t], c);
    }
}

// ------- fold shadow histograms into bigh + per-chunk partial sums ---------
__global__ void fold_psum_kernel(int* __restrict__ bigh,
                                 const int* __restrict__ smallh,
                                 int* __restrict__ psum)
{
    __shared__ int red[256];
    int blk = blockIdx.x;            // g*NCH + c
    int g = blk / NCH, c = blk % NCH;
    int tid = threadIdx.x;
    int t = c * CHUNK + tid;
    int v = 0;
    if (t < HBINS) {
        size_t bi = (size_t)g * HBINS + t;
        v = bigh[bi];
        if (t < LBINS) {
            const int* gs = smallh + (size_t)g * NSMALL * LBINS + t;
            #pragma unroll
            for (int s = 0; s < NSMALL; ++s) v += gs[s * LBINS];
            bigh[bi] = v;
        }
    }
    red[tid] = v;
    __syncthreads();
    for (int o = 128; o > 0; o >>= 1) {
        if (tid < o) red[tid] += red[tid + o];
        __syncthreads();
    }
    if (tid == 0) psum[blk] = red[0];
}

// ---------------- percentile (torch.quantile-style linear interp) ----------
__global__ void percentile2_kernel(const int* __restrict__ bigh,
                                   const int* __restrict__ psum,
                                   float* __restrict__ h)
{
    __shared__ int ps[256];
    __shared__ int chunkidx, chunkbase;
    __shared__ int sel[2];
    int g = blockIdx.x;
    int tid = threadIdx.x;              // 256

    if (tid == 0) { chunkidx = 0; chunkbase = 0; sel[0] = 0; sel[1] = 0; }

    int myv = (tid < NCH) ? psum[g * NCH + tid] : 0;
    ps[tid] = myv;
    __syncthreads();
    for (int o = 1; o < 256; o <<= 1) {
        int t = (tid >= o) ? ps[tid - o] : 0;
        __syncthreads();
        ps[tid] += t;
        __syncthreads();
    }
    int n = ps[255];
    int incl = ps[tid];
    int excl = incl - myv;

    float pos = 0.95f * (float)(n - 1);
    float fpos = floorf(pos);
    int lo = (int)fpos;
    int nm1 = n - 1; if (nm1 < 0) nm1 = 0;
    if (lo < 0) lo = 0;
    if (lo > nm1) lo = nm1;
    int hi = lo + 1; if (hi > nm1) hi = nm1;
    float frac = pos - fpos;

    for (int ri = 0; ri < 2; ++ri) {
        int r = ri ? hi : lo;
        if (r >= excl && r < incl) {        // unique owner thread
            chunkidx = tid; chunkbase = excl;
        }
        __syncthreads();
        int c = chunkidx, base = chunkbase;
        int t2 = c * CHUNK + tid;
        int cnt = (t2 < HBINS) ? bigh[(size_t)g * HBINS + t2] : 0;
        __syncthreads();
        ps[tid] = cnt;
        __syncthreads();
        for (int o = 1; o < 256; o <<= 1) {
            int t = (tid >= o) ? ps[tid - o] : 0;
            __syncthreads();
            ps[tid] += t;
            __syncthreads();
        }
        int incl2 = base + ps[tid];
        int excl2 = incl2 - cnt;
        if (r >= excl2 && r < incl2) sel[ri] = t2;
        __syncthreads();
    }
    if (tid == 0) {
        float a = sqrtf((float)sel[0]);
        float b = sqrtf((float)sel[1]);
        h[g] = a + frac * (b - a);
    }
}

// ---------------- final: non-directed HD95 = max of the two directions -----
__global__ void final_kernel(const float* __restrict__ h, float* __restrict__ out)
{
    int b = threadIdx.x;
    if (b < BB) out[b] = fmaxf(h[b*2 + 0], h[b*2 + 1]);
}

extern "C" void kernel_launch(void* const* d_in, const int* in_sizes, int n_in,
                              void* d_out, int out_size, void* d_ws, size_t ws_size,
                              hipStream_t stream)
{
    const float* pred = (const float*)d_in[0];
    const float* targ = (const float*)d_in[1];
    float* out = (float*)d_out;

    uint8_t* ws = (uint8_t*)d_ws;
    uint8_t* ep = ws;                          // TOTAL bytes
    uint8_t* eg = ep + TOTAL;                  // TOTAL bytes
    int* dbuf   = (int*)(eg + TOTAL);          // TOTAL ints
    int* bigh   = dbuf + TOTAL;                // 4 * HBINS ints
    int* smallh = bigh + 4 * HBINS;            // 4 * NSMALL * LBINS ints
    int* psum   = smallh + 4 * NSMALL * LBINS; // 4 * NCH ints
    float* h    = (float*)(psum + 4 * NCH);    // 4 floats

    hipMemsetAsync(bigh, 0, ((size_t)4 * HBINS + (size_t)4 * NSMALL * LBINS) * sizeof(int), stream);

    edges_kernel<<<(TOTAL/4)/256, 256, 0, stream>>>(pred, targ, (uint32_t*)ep, (uint32_t*)eg);

    // dir 0: EDT of gt edges, histogrammed at pred-edge voxels
    edt_pass_x<<<BB*DD*HH, WW, 0, stream>>>(eg, dbuf);
    edt_pass_y<<<BB*DD*(WW/TXY), 1024, 0, stream>>>(dbuf);
    edt_pass_z_hist<<<BB*HH*(WW/TXZ), 1024, 0, stream>>>(dbuf, ep, bigh, smallh, 0);

    // dir 1: EDT of pred edges, histogrammed at gt-edge voxels
    edt_pass_x<<<BB*DD*HH, WW, 0, stream>>>(ep, dbuf);
    edt_pass_y<<<BB*DD*(WW/TXY), 1024, 0, stream>>>(dbuf);
    edt_pass_z_hist<<<BB*HH*(WW/TXZ), 1024, 0, stream>>>(dbuf, eg, bigh, smallh, 1);

    fold_psum_kernel<<<4 * NCH, 256, 0, stream>>>(bigh, smallh, psum);
    percentile2_kernel<<<4, 256, 0, stream>>>(bigh, psum, h);
    final_kernel<<<1, 64, 0, stream>>>(h, out);
}

// Round 5
// 58.213 us; speedup vs baseline: 5.6632x; 1.9409x over previous
//
#include <hip/hip_runtime.h>
#include <stdint.h>

#define BB 2
#define DD 64
#define HH 128
#define WW 128
#define NVOX (DD*HH*WW)        // 1048576 per batch (2^20)
#define TOTAL (BB*NVOX)        // 2097152
#define INF16 65535
#define HBINS 36868            // > max finite dsq (36227)
#define LBINS 4096
#define NSMALL 7               // shadow slots (LBINS bins each); slot0 = full
#define CHUNK 256
#define NCH ((HBINS + CHUNK - 1) / CHUNK)      // 145
#define HISTINTS (4*HBINS + 4*NSMALL*LBINS)    // 262160 ints, bigh||smallh contiguous

// ---------- edges (m & ~erosion, 6-neigh, border=False) + zero hist --------
__global__ void edges_zero_kernel(const float* __restrict__ pred,
                                  const float* __restrict__ targ,
                                  uint32_t* __restrict__ ep,
                                  uint32_t* __restrict__ eg,
                                  int* __restrict__ hist)
{
    int i = blockIdx.x * blockDim.x + threadIdx.x;   // quad index
    if (i < HISTINTS) hist[i] = 0;
    if (i >= TOTAL/4) return;
    int idx = i * 4;
    int x0 = idx & (WW-1);
    int y  = (idx >> 7) & (HH-1);
    int z  = (idx >> 14) & (DD-1);

    const float* srcs[2] = {pred, targ};
    uint32_t* dsts[2] = {ep, eg};
    const float4 zero4 = make_float4(0.f, 0.f, 0.f, 0.f);
    #pragma unroll
    for (int s = 0; s < 2; ++s) {
        const float* src = srcs[s];
        const float4* src4 = (const float4*)src;
        float4 c = src4[i];
        float lft = (x0 > 0)      ? src[idx - 1] : 0.f;
        float rgt = (x0 + 4 < WW) ? src[idx + 4] : 0.f;
        float4 ym = (y > 0)    ? src4[i - WW/4]      : zero4;
        float4 yp = (y < HH-1) ? src4[i + WW/4]      : zero4;
        float4 zm = (z > 0)    ? src4[i - (HH*WW)/4] : zero4;
        float4 zp = (z < DD-1) ? src4[i + (HH*WW)/4] : zero4;
        bool m0 = c.x > 0.5f, m1 = c.y > 0.5f, m2 = c.z > 0.5f, m3 = c.w > 0.5f;
        bool e0 = m0 && !((lft>0.5f) && m1 && (ym.x>0.5f) && (yp.x>0.5f) && (zm.x>0.5f) && (zp.x>0.5f));
        bool e1 = m1 && !(m0 && m2 && (ym.y>0.5f) && (yp.y>0.5f) && (zm.y>0.5f) && (zp.y>0.5f));
        bool e2 = m2 && !(m1 && m3 && (ym.z>0.5f) && (yp.z>0.5f) && (zm.z>0.5f) && (zp.z>0.5f));
        bool e3 = m3 && !(m2 && (rgt>0.5f) && (ym.w>0.5f) && (yp.w>0.5f) && (zm.w>0.5f) && (zp.w>0.5f));
        dsts[s][i] = (uint32_t)e0 | ((uint32_t)e1 << 8) | ((uint32_t)e2 << 16) | ((uint32_t)e3 << 24);
    }
}

// ---------- nearest set bit at position >= x in 128-bit mask (hi:lo) -------
__device__ __forceinline__ int dist128(uint64_t lo, uint64_t hi, int x)
{
    uint64_t a, b;
    if (x == 0)      { a = lo; b = hi; }
    else if (x < 64) { a = (lo >> x) | (hi << (64 - x)); b = hi >> x; }
    else             { a = hi >> (x - 64); b = 0; }
    if (a) return __builtin_ctzll(a);
    if (b) return 64 + __builtin_ctzll(b);
    return 999;
}

// ---------- fused x+y EDT for one z-slice, both directions ----------------
// x-EDT: O(1)/voxel via 128-bit row bitmask. y-EDT: early-exit over LDS tile.
#define TPITCH 132   // ushort pitch for t16 (breaks row bank aliasing)
__global__ __launch_bounds__(1024)
void edt_xy_kernel(const uint8_t* __restrict__ ep,
                   const uint8_t* __restrict__ eg,
                   uint16_t* __restrict__ d0,
                   uint16_t* __restrict__ d1)
{
    __shared__ uint16_t t16[HH * TPITCH];
    int blk = blockIdx.x;            // (b*DD+z)*2 + dir
    int dir = blk & 1;
    int bz  = blk >> 1;              // b*DD + z
    const uint8_t* mask = dir ? ep : eg;   // dir0: EDT of gt edges
    uint16_t* dout = dir ? d1 : d0;
    size_t sbase = (size_t)bz * (HH * WW);
    int tid = threadIdx.x;           // 1024
    int row = tid >> 3;              // 0..127  (y)
    int seg = tid & 7;               // 16 bytes each

    // load 16 mask bytes, squish to 16 bits
    uint4 mv = ((const uint4*)(mask + sbase))[tid];
    uint32_t b0 = ((mv.x & 0x01010101u) * 0x01020408u) >> 24;
    uint32_t b1 = ((mv.y & 0x01010101u) * 0x01020408u) >> 24;
    uint32_t b2 = ((mv.z & 0x01010101u) * 0x01020408u) >> 24;
    uint32_t b3 = ((mv.w & 0x01010101u) * 0x01020408u) >> 24;
    int bits16 = (int)(b0 | (b1 << 4) | (b2 << 8) | (b3 << 12));
    // assemble full 128-bit row mask from the 8 lanes of this row (same wave)
    int lanebase = (tid & 63) & ~7;
    uint64_t lo = 0, hi = 0;
    #pragma unroll
    for (int j = 0; j < 4; ++j) {
        lo |= ((uint64_t)((uint32_t)__shfl(bits16, lanebase + j, 64) & 0xFFFFu)) << (16 * j);
        hi |= ((uint64_t)((uint32_t)__shfl(bits16, lanebase + 4 + j, 64) & 0xFFFFu)) << (16 * j);
    }
    uint64_t rlo = __brevll(hi), rhi = __brevll(lo);   // bit-reversed 128-bit

    #pragma unroll
    for (int j = 0; j < 16; ++j) {
        int x = seg * 16 + j;
        int dr = dist128(lo, hi, x);
        int dl = dist128(rlo, rhi, 127 - x);
        int dist = min(dr, dl);
        int dsq = (dist > 127) ? INF16 : dist * dist;
        t16[row * TPITCH + x] = (uint16_t)dsq;
    }
    __syncthreads();

    // y pass: xx = tid&127 (wave-uniform y), 16 outputs per thread
    int xx = tid & 127;
    int yg = tid >> 7;               // 0..7
    for (int k = 0; k < 16; ++k) {
        int y = yg + k * 8;
        int best = t16[y * TPITCH + xx];
        for (int o = 1; o < HH && o * o < best; ++o) {
            int osq = o * o;
            int ylo = y - o, yhi = y + o;
            if (ylo >= 0) best = min(best, (int)t16[ylo * TPITCH + xx] + osq);
            if (yhi < HH) best = min(best, (int)t16[yhi * TPITCH + xx] + osq);
        }
        dout[sbase + (size_t)y * WW + xx] = (uint16_t)best;
    }
}

// ---------- z EDT + histogram, both directions ----------------------------
#define ZPITCH 68    // ushort pitch (8B-aligned rows, bank-staggered)
__global__ __launch_bounds__(1024)
void edt_z_hist_kernel(const uint16_t* __restrict__ d0,
                       const uint16_t* __restrict__ d1,
                       const uint8_t* __restrict__ ep,
                       const uint8_t* __restrict__ eg,
                       int* __restrict__ bigh,
                       int* __restrict__ smallh)
{
    __shared__ uint16_t tile[DD * ZPITCH];
    __shared__ int lh[LBINS];
    int tid = threadIdx.x;           // 1024
    for (int t = tid; t < LBINS; t += 1024) lh[t] = 0;

    int blk = blockIdx.x;            // dir | xt<<1 | y<<2 | b<<9
    int dir = blk & 1;
    int xt  = (blk >> 1) & 1;
    int y   = (blk >> 2) & 127;
    int b   = blk >> 9;
    const uint16_t* d = dir ? d1 : d0;
    const uint8_t* evalmask = dir ? eg : ep;  // dir0: histogram at pred edges
    size_t base = (size_t)b * NVOX + (size_t)y * WW + xt * 64;   // voxel units

    {   // cooperative load: 64 z-rows x 128B
        int z = tid >> 4, sg = tid & 15;
        uint2 v = *(const uint2*)(d + base + (size_t)z * (HH * WW) + sg * 4);
        *(uint2*)&tile[z * ZPITCH + sg * 4] = v;
    }
    __syncthreads();

    int xx = tid & 63;
    int zg = tid >> 6;               // 0..15
    int g = b * 2 + dir;
    int* gbig = bigh + (size_t)g * HBINS;
    int lane = tid & 63;

    int bestv[4]; int validv[4];
    #pragma unroll
    for (int k = 0; k < 4; ++k) {
        int z = zg + k * 16;
        int best = tile[z * ZPITCH + xx];
        for (int o = 1; o < DD && o * o < best; ++o) {
            int osq = o * o;
            int zlo = z - o, zhi = z + o;
            if (zlo >= 0) best = min(best, (int)tile[zlo * ZPITCH + xx] + osq);
            if (zhi < DD) best = min(best, (int)tile[zhi * ZPITCH + xx] + osq);
        }
        bestv[k] = best;
        validv[k] = evalmask[base + (size_t)z * (HH * WW) + xx];
    }

    #pragma unroll
    for (int k = 0; k < 4; ++k) {
        int v = bestv[k]; if (v >= HBINS) v = HBINS - 1;
        bool valid = validv[k] != 0;
        unsigned long long active = __ballot(valid);
        while (active) {
            int leader = __ffsll(active) - 1;
            int lv = __shfl(v, leader, 64);
            unsigned long long same = __ballot(valid && (v == lv));
            if (lane == leader) {
                int cnt = __popcll(same);
                if (lv < LBINS) atomicAdd(&lh[lv], cnt);
                else            atomicAdd(&gbig[lv], cnt);
            }
            active &= ~same;
        }
    }
    __syncthreads();
    int slot = (blk >> 1) & 7;       // spread over 8 targets per g
    int* dst = (slot == 0) ? gbig : (smallh + ((size_t)g * NSMALL + (slot - 1)) * LBINS);
    for (int t = tid; t < LBINS; t += 1024) {
        int c = lh[t];
        if (c) atomicAdd(&dst[t], c);
    }
}

// ------- fold shadow histograms into bigh + per-chunk partial sums ---------
__global__ void fold_psum_kernel(int* __restrict__ bigh,
                                 const int* __restrict__ smallh,
                                 int* __restrict__ psum)
{
    __shared__ int red[256];
    int blk = blockIdx.x;            // g*NCH + c
    int g = blk / NCH, c = blk % NCH;
    int tid = threadIdx.x;
    int t = c * CHUNK + tid;
    int v = 0;
    if (t < HBINS) {
        size_t bi = (size_t)g * HBINS + t;
        v = bigh[bi];
        if (t < LBINS) {
            const int* gs = smallh + (size_t)g * NSMALL * LBINS + t;
            #pragma unroll
            for (int s = 0; s < NSMALL; ++s) v += gs[s * LBINS];
            bigh[bi] = v;
        }
    }
    red[tid] = v;
    __syncthreads();
    for (int o = 128; o > 0; o >>= 1) {
        if (tid < o) red[tid] += red[tid + o];
        __syncthreads();
    }
    if (tid == 0) psum[blk] = red[0];
}

// ---------------- percentile + fused final max -----------------------------
__global__ void percentile2_kernel(const int* __restrict__ bigh,
                                   const int* __restrict__ psum,
                                   float* __restrict__ out)
{
    __shared__ int ps[256];
    __shared__ int chunkidx, chunkbase;
    __shared__ int sel[2];
    int g = blockIdx.x;
    int tid = threadIdx.x;              // 256

    if (tid == 0) { chunkidx = 0; chunkbase = 0; sel[0] = 0; sel[1] = 0; }

    int myv = (tid < NCH) ? psum[g * NCH + tid] : 0;
    ps[tid] = myv;
    __syncthreads();
    for (int o = 1; o < 256; o <<= 1) {
        int t = (tid >= o) ? ps[tid - o] : 0;
        __syncthreads();
        ps[tid] += t;
        __syncthreads();
    }
    int n = ps[255];
    int incl = ps[tid];
    int excl = incl - myv;

    float pos = 0.95f * (float)(n - 1);
    float fpos = floorf(pos);
    int lo = (int)fpos;
    int nm1 = n - 1; if (nm1 < 0) nm1 = 0;
    if (lo < 0) lo = 0;
    if (lo > nm1) lo = nm1;
    int hi = lo + 1; if (hi > nm1) hi = nm1;
    float frac = pos - fpos;

    for (int ri = 0; ri < 2; ++ri) {
        int r = ri ? hi : lo;
        if (r >= excl && r < incl) {        // unique owner
            chunkidx = tid; chunkbase = excl;
        }
        __syncthreads();
        int c = chunkidx, base = chunkbase;
        int t2 = c * CHUNK + tid;
        int cnt = (t2 < HBINS) ? bigh[(size_t)g * HBINS + t2] : 0;
        __syncthreads();
        ps[tid] = cnt;
        __syncthreads();
        for (int o = 1; o < 256; o <<= 1) {
            int t = (tid >= o) ? ps[tid - o] : 0;
            __syncthreads();
            ps[tid] += t;
            __syncthreads();
        }
        int incl2 = base + ps[tid];
        int excl2 = incl2 - cnt;
        if (r >= excl2 && r < incl2) sel[ri] = t2;
        __syncthreads();
    }
    if (tid == 0) {
        float a = sqrtf((float)sel[0]);
        float bv = sqrtf((float)sel[1]);
        float val = a + frac * (bv - a);
        // out[b] = max over the two directions; float>=0 so int-compare works.
        atomicMax((int*)out + (g >> 1), __float_as_int(val));
    }
}

extern "C" void kernel_launch(void* const* d_in, const int* in_sizes, int n_in,
                              void* d_out, int out_size, void* d_ws, size_t ws_size,
                              hipStream_t stream)
{
    const float* pred = (const float*)d_in[0];
    const float* targ = (const float*)d_in[1];
    float* out = (float*)d_out;

    uint8_t* ws = (uint8_t*)d_ws;
    uint8_t* ep  = ws;                               // TOTAL bytes
    uint8_t* eg  = ep + TOTAL;                       // TOTAL bytes
    uint16_t* d0 = (uint16_t*)(eg + TOTAL);          // TOTAL ushorts
    uint16_t* d1 = d0 + TOTAL;                       // TOTAL ushorts
    int* bigh    = (int*)(d1 + TOTAL);               // 4*HBINS ints
    int* smallh  = bigh + 4 * HBINS;                 // 4*NSMALL*LBINS ints (contiguous after bigh)
    int* psum    = smallh + 4 * NSMALL * LBINS;      // 4*NCH ints

    edges_zero_kernel<<<(TOTAL/4)/256, 256, 0, stream>>>(pred, targ,
                                                         (uint32_t*)ep, (uint32_t*)eg, bigh);
    edt_xy_kernel<<<BB*DD*2, 1024, 0, stream>>>(ep, eg, d0, d1);
    edt_z_hist_kernel<<<BB*HH*2*2, 1024, 0, stream>>>(d0, d1, ep, eg, bigh, smallh);
    fold_psum_kernel<<<4 * NCH, 256, 0, stream>>>(bigh, smallh, psum);
    percentile2_kernel<<<4, 256, 0, stream>>>(bigh, psum, out);
}